// Round 4
// baseline (1622.162 us; speedup 1.0000x reference)
//
#include <hip/hip_runtime.h>
#include <math.h>

#define Bn 8
#define Vn 5000
#define Cn 256
#define Kn 200

// workspace layout (floats):
//   AB  [16][200][256] @ 0        (mats 0..7 = A per batch, 8..15 = Bc per batch)
//   AAT [16][200][200] @ 819200   (mats 0..7 = A·Aᵀ,      8..15 = B·Aᵀ)
#define AB_OFF  0
#define AAT_OFF 819200

// ---------------------------------------------------------------------------
// K1: A[b] = evecs_trans_x[b] (200x5000) @ feat_x[b] (5000x256), same for y.
// 16 GEMMs, splitK=16, atomicAdd accumulate. 128x128 tile, BK=16, 8x8 micro.
// LDS tiles transposed [kk][row] so A- and B-fragments are b128 loads.
// ---------------------------------------------------------------------------
__global__ __launch_bounds__(256, 4) void k_gemm_ab(
    const float* __restrict__ fx, const float* __restrict__ fy,
    const float* __restrict__ etx, const float* __restrict__ ety,
    float* __restrict__ AB)
{
    __shared__ __align__(16) float Es[16 * 132];   // [kk][row]
    __shared__ __align__(16) float Fs[16 * 132];   // [kk][col]
    const int bid  = blockIdx.x;
    const int ks   = bid & 15;
    const int t    = bid >> 4;
    const int mat  = t >> 2;
    const int tile = t & 3;
    const int row0 = (tile >> 1) * 128;
    const int col0 = (tile & 1) * 128;
    const int b = mat & 7, which = mat >> 3;
    const float* __restrict__ E = (which ? ety : etx) + b * Kn * Vn;
    const float* __restrict__ F = (which ? fy : fx) + b * Vn * Cn;
    float* __restrict__ out = AB + mat * Kn * Cn;
    const int kstart = ks * 320;
    const int kend = (kstart + 320 < Vn) ? (kstart + 320) : Vn;
    const int tid = threadIdx.x;
    const int tx = tid & 15, ty = tid >> 4;
    float acc[8][8] = {};

    for (int k0 = kstart; k0 < kend; k0 += 16) {
        // stage E: 128 rows x 16 kk (transposed store)
#pragma unroll
        for (int i = 0; i < 2; ++i) {
            int id = tid + i * 256;
            int row = id >> 2;
            int kq = (id & 3) << 2;
            int gr = row0 + row;
            float4 v = make_float4(0.f, 0.f, 0.f, 0.f);
            if (gr < Kn && k0 + kq < kend)
                v = *(const float4*)&E[gr * Vn + k0 + kq];
            Es[(kq + 0) * 132 + row] = v.x;
            Es[(kq + 1) * 132 + row] = v.y;
            Es[(kq + 2) * 132 + row] = v.z;
            Es[(kq + 3) * 132 + row] = v.w;
        }
        // stage F: 16 v x 128 cols (direct b128 store)
#pragma unroll
        for (int i = 0; i < 2; ++i) {
            int id = tid + i * 256;
            int v = id >> 5;
            int cq = (id & 31) << 2;
            float4 wv = make_float4(0.f, 0.f, 0.f, 0.f);
            if (k0 + v < kend)
                wv = *(const float4*)&F[(k0 + v) * Cn + col0 + cq];
            *(float4*)&Fs[v * 132 + cq] = wv;
        }
        __syncthreads();
#pragma unroll
        for (int kk = 0; kk < 16; ++kk) {
            float4 a0 = *(const float4*)&Es[kk * 132 + ty * 8];
            float4 a1 = *(const float4*)&Es[kk * 132 + ty * 8 + 4];
            float4 b0 = *(const float4*)&Fs[kk * 132 + tx * 8];
            float4 b1 = *(const float4*)&Fs[kk * 132 + tx * 8 + 4];
            float av[8] = {a0.x,a0.y,a0.z,a0.w,a1.x,a1.y,a1.z,a1.w};
            float bv[8] = {b0.x,b0.y,b0.z,b0.w,b1.x,b1.y,b1.z,b1.w};
#pragma unroll
            for (int m = 0; m < 8; ++m)
#pragma unroll
                for (int n = 0; n < 8; ++n)
                    acc[m][n] += av[m] * bv[n];
        }
        __syncthreads();
    }
#pragma unroll
    for (int m = 0; m < 8; ++m) {
        int gr = row0 + ty * 8 + m;
        if (gr < Kn) {
#pragma unroll
            for (int n = 0; n < 8; ++n)
                atomicAdd(&out[gr * Cn + col0 + tx * 8 + n], acc[m][n]);
        }
    }
}

// ---------------------------------------------------------------------------
// K2: AAT[m] = X[m] (200x256) @ A2ᵀ (256x200). Transposed LDS [kk][row]:
// one b128 per operand per kk (4x4 micro).
// ---------------------------------------------------------------------------
__global__ __launch_bounds__(256) void k_gemm_nt(
    const float* __restrict__ AB, float* __restrict__ AAT)
{
    __shared__ __align__(16) float Xs[32 * 68];   // [kk][row]
    __shared__ __align__(16) float As[32 * 68];
    const int bid = blockIdx.x;
    const int mat = bid >> 4;
    const int tile = bid & 15;
    const int tr = tile >> 2, tc = tile & 3;
    const float* __restrict__ X  = AB + mat * Kn * Cn;
    const float* __restrict__ A2 = AB + (mat & 7) * Kn * Cn;
    float* __restrict__ out = AAT + mat * Kn * Kn;
    const int r0 = tr * 64, j0 = tc * 64;
    const int tid = threadIdx.x;
    const int tx = tid & 15, ty = tid >> 4;
    float acc[4][4] = {};

    for (int c0 = 0; c0 < Cn; c0 += 32) {
#pragma unroll
        for (int i = 0; i < 2; ++i) {
            int id = tid + i * 256;
            int row = id >> 3;
            int kq = (id & 7) << 2;
            int gr = r0 + row;
            float4 v = (gr < Kn) ? *(const float4*)&X[gr * Cn + c0 + kq]
                                 : make_float4(0.f, 0.f, 0.f, 0.f);
            Xs[(kq + 0) * 68 + row] = v.x;
            Xs[(kq + 1) * 68 + row] = v.y;
            Xs[(kq + 2) * 68 + row] = v.z;
            Xs[(kq + 3) * 68 + row] = v.w;
            int gj = j0 + row;
            float4 u = (gj < Kn) ? *(const float4*)&A2[gj * Cn + c0 + kq]
                                 : make_float4(0.f, 0.f, 0.f, 0.f);
            As[(kq + 0) * 68 + row] = u.x;
            As[(kq + 1) * 68 + row] = u.y;
            As[(kq + 2) * 68 + row] = u.z;
            As[(kq + 3) * 68 + row] = u.w;
        }
        __syncthreads();
#pragma unroll
        for (int kk = 0; kk < 32; ++kk) {
            float4 a = *(const float4*)&Xs[kk * 68 + ty * 4];
            float4 bb = *(const float4*)&As[kk * 68 + tx * 4];
            float av[4] = {a.x, a.y, a.z, a.w};
            float bv[4] = {bb.x, bb.y, bb.z, bb.w};
#pragma unroll
            for (int m = 0; m < 4; ++m)
#pragma unroll
                for (int n = 0; n < 4; ++n)
                    acc[m][n] += av[m] * bv[n];
        }
        __syncthreads();
    }
#pragma unroll
    for (int m = 0; m < 4; ++m) {
        int gr = r0 + ty * 4 + m;
        if (gr < Kn) {
#pragma unroll
            for (int n = 0; n < 4; ++n) {
                int gj = j0 + tx * 4 + n;
                if (gj < Kn) out[gr * Kn + gj] = acc[m][n];
            }
        }
    }
}

// ---------------------------------------------------------------------------
// K3: per (b,i): solve (AAt[b] + lambda*diag(D[b,i,:])) x = BAt[b,i,:].
// sM[200][200] (stride 200, b128-aligned rows) + sR4[200][4] padded RHS +
// sUr4[16][4] (U-applied RHS of panel rows, comps 1..3 stay 0).
// Blocked no-pivot LU, NB=16 (12 steps) + 8x8 epilogue:
//   P: wave 0 factors 200x16 panel in registers (shfl broadcasts).
//   U: one col/thread, depth-16 register recurrence; L-rows read as b128.
//   T: rank-16 trailing update, 4 consecutive cols per lane (b128 r/w),
//      f row-slice 4xb128 broadcast, U-block in 16 float4 regs; RHS column
//      handled by lane nl via pointer-select into sR4/sUr4.
// Back-substitution: 4-column groups, b128 column reads, x via shfl.
// ---------------------------------------------------------------------------
__global__ __launch_bounds__(512, 2) void k_solve(
    const float* __restrict__ AAT,
    const float* __restrict__ evalx, const float* __restrict__ evaly,
    const float* __restrict__ graw, const float* __restrict__ lraw,
    float* __restrict__ out)
{
    __shared__ __align__(16) float sM[Kn * 200];
    __shared__ __align__(16) float sR4[Kn * 4];
    __shared__ __align__(16) float sUr4[16 * 4];
    __shared__ float sAux[8];
    const int bid = blockIdx.x;
    const int b = bid / 200;
    const int tid = threadIdx.x;
    const int i = bid - b * 200;
    const float* __restrict__ Sb = AAT + b * 40000;
    const float* __restrict__ Rb = AAT + 320000 + bid * 200;
    const float* __restrict__ ex = evalx + b * Kn;
    const float* __restrict__ ey = evaly + b * Kn;
    const int w = tid >> 6, l = tid & 63;

    // load S (stride 200, straight b128 copy) and RHS (padded, comps1..3=0)
    {
        const float4* Sb4 = (const float4*)Sb;
        float4* sM4 = (float4*)sM;
        for (int e = tid; e < 10000; e += 512) sM4[e] = Sb4[e];
    }
    if (tid < Kn) *(float4*)&sR4[tid * 4] = make_float4(Rb[tid], 0.f, 0.f, 0.f);
    if (tid < 64) sUr4[tid] = 0.f;

    // scaling = max(max ex, max ey) over the batch (wave 0)
    if (tid < 64) {
        float mx = 0.f;
        for (int j2 = tid; j2 < Kn; j2 += 64) mx = fmaxf(mx, fmaxf(ex[j2], ey[j2]));
#pragma unroll
        for (int s = 32; s > 0; s >>= 1) mx = fmaxf(mx, __shfl_down(mx, s));
        if (tid == 0) sAux[0] = mx;
    }
    __syncthreads();

    // diagonal: += lambda * D[b,i,r]
    if (tid < Kn) {
        int r = tid;
        float s = sAux[0];
        float g = 1.f / (1.f + expf(-graw[0]));
        float lr = lraw[0];
        float sp = fmaxf(lr, 0.f) + log1pf(expf(-fabsf(lr)));   // stable softplus
        float lmb = 10.f + sp * (990.f / 1000.f);
        lmb = fminf(fmaxf(lmb, 10.f), 1000.f);
        float gx = powf(ex[i] / s, g);
        float gy = powf(ey[r] / s, g);
        float d1 = 1.f / (gx * gx + 1.f);
        float d2 = 1.f / (gy * gy + 1.f);
        float re = gy * d2 - gx * d1;
        float im = d2 - d1;
        sM[r * 200 + r] += lmb * (re * re + im * im);
    }
    __syncthreads();

    // blocked LU, NB = 16, 12 steps (cols 0..191)
    for (int k = 0; k < 192; k += 16) {
        const int jb0 = k + 16;

        // ---- phase P: wave 0 factors the panel (rows k..199, cols k..k+15)
        if (tid < 64) {
            float p[4][16];
#pragma unroll
            for (int q = 0; q < 4; ++q) {
                int r = k + l + 64 * q;
                if (r < Kn) {
#pragma unroll
                    for (int jq = 0; jq < 4; ++jq) {
                        float4 v = *(const float4*)&sM[r * 200 + k + jq * 4];
                        p[q][jq * 4 + 0] = v.x; p[q][jq * 4 + 1] = v.y;
                        p[q][jq * 4 + 2] = v.z; p[q][jq * 4 + 3] = v.w;
                    }
                } else {
#pragma unroll
                    for (int j2 = 0; j2 < 16; ++j2) p[q][j2] = 0.f;
                }
            }
#pragma unroll
            for (int c = 0; c < 16; ++c) {
                float pivc = __shfl(p[0][c], c);
                float invp = 1.0f / pivc;
                float pr[16];
#pragma unroll
                for (int j2 = 0; j2 < 16; ++j2)
                    if (j2 > c) pr[j2] = __shfl(p[0][j2], c);
#pragma unroll
                for (int q = 0; q < 4; ++q) {
                    int r = k + l + 64 * q;
                    bool act = (r < Kn) && (q > 0 || l > c);
                    if (act) {
                        float f = p[q][c] * invp;
                        p[q][c] = f;
#pragma unroll
                        for (int j2 = 0; j2 < 16; ++j2)
                            if (j2 > c) p[q][j2] -= f * pr[j2];
                    }
                }
            }
#pragma unroll
            for (int q = 0; q < 4; ++q) {
                int r = k + l + 64 * q;
                if (r < Kn) {
#pragma unroll
                    for (int jq = 0; jq < 4; ++jq) {
                        *(float4*)&sM[r * 200 + k + jq * 4] =
                            make_float4(p[q][jq * 4 + 0], p[q][jq * 4 + 1],
                                        p[q][jq * 4 + 2], p[q][jq * 4 + 3]);
                    }
                }
            }
        }
        __syncthreads();

        // ---- phase U: apply L16^{-1} to rows k..k+15, cols jb0..199 + RHS
        {
            const int nt = 184 - k;          // thread nt handles the RHS col
            if (tid <= nt) {
                const bool rhs = (tid == nt);
                const int j = jb0 + tid;
                float u[16];
                if (!rhs) {
#pragma unroll
                    for (int c = 0; c < 16; ++c) u[c] = sM[(k + c) * 200 + j];
                } else {
#pragma unroll
                    for (int c = 0; c < 16; ++c) u[c] = sR4[(k + c) * 4];
                }
#pragma unroll
                for (int c = 1; c < 16; ++c) {
                    float4 Lr[4];
#pragma unroll
                    for (int mq = 0; mq < 4; ++mq)
                        if (mq * 4 < c)
                            Lr[mq] = *(const float4*)&sM[(k + c) * 200 + k + mq * 4];
                    float a = u[c];
#pragma unroll
                    for (int c2 = 0; c2 < 16; ++c2)
                        if (c2 < c) a -= ((const float*)Lr)[c2] * u[c2];
                    u[c] = a;
                }
                if (!rhs) {
#pragma unroll
                    for (int c = 0; c < 16; ++c) sM[(k + c) * 200 + j] = u[c];
                } else {
#pragma unroll
                    for (int c = 0; c < 16; ++c) {
                        sR4[(k + c) * 4] = u[c];
                        sUr4[c * 4] = u[c];
                    }
                }
            }
        }
        __syncthreads();

        // ---- phase T: rank-16 trailing update, rows jb0..199
        {
            const int nl = (184 - k) >> 2;   // lane nl handles the RHS col
            if (l <= nl) {
                const bool rhs = (l == nl);
                const float* pvbase = rhs ? sUr4 : &sM[k * 200 + jb0 + 4 * l];
                const int pvstride = rhs ? 4 : 200;
                float4 pv[16];
#pragma unroll
                for (int c = 0; c < 16; ++c)
                    pv[c] = *(const float4*)&pvbase[c * pvstride];
                float* crow = rhs ? sR4 : &sM[jb0 + 4 * l];
                const int cstride = rhs ? 4 : 200;
                for (int r = jb0 + w; r < Kn; r += 8) {
                    const float* fr = &sM[r * 200 + k];
                    float4 f0 = *(const float4*)&fr[0];
                    float4 f1 = *(const float4*)&fr[4];
                    float4 f2 = *(const float4*)&fr[8];
                    float4 f3 = *(const float4*)&fr[12];
                    float fv[16] = {f0.x,f0.y,f0.z,f0.w, f1.x,f1.y,f1.z,f1.w,
                                    f2.x,f2.y,f2.z,f2.w, f3.x,f3.y,f3.z,f3.w};
                    float4 cv = *(const float4*)&crow[r * cstride];
#pragma unroll
                    for (int c = 0; c < 16; ++c) {
                        cv.x -= fv[c] * pv[c].x;
                        cv.y -= fv[c] * pv[c].y;
                        cv.z -= fv[c] * pv[c].z;
                        cv.w -= fv[c] * pv[c].w;
                    }
                    *(float4*)&crow[r * cstride] = cv;
                }
            }
        }
        __syncthreads();
    }

    // ---- epilogue: factor trailing 8x8 block (rows/cols 192..199) + RHS
    if (tid < 64) {
        float e[9];
        const int r = 192 + l;
        const bool act = (l < 8);
        if (act) {
            float4 t0 = *(const float4*)&sM[r * 200 + 192];
            float4 t1 = *(const float4*)&sM[r * 200 + 196];
            e[0] = t0.x; e[1] = t0.y; e[2] = t0.z; e[3] = t0.w;
            e[4] = t1.x; e[5] = t1.y; e[6] = t1.z; e[7] = t1.w;
            e[8] = sR4[r * 4];
        } else {
#pragma unroll
            for (int j2 = 0; j2 < 9; ++j2) e[j2] = 0.f;
        }
#pragma unroll
        for (int c = 0; c < 8; ++c) {
            float pive = __shfl(e[c], c);
            float invp = 1.0f / pive;
            float pr[9];
#pragma unroll
            for (int j2 = 0; j2 < 9; ++j2)
                if (j2 > c) pr[j2] = __shfl(e[j2], c);
            if (act && l > c) {
                float f = e[c] * invp;
#pragma unroll
                for (int j2 = 0; j2 < 9; ++j2)
                    if (j2 > c) e[j2] -= f * pr[j2];
            }
        }
        if (act) {
            *(float4*)&sM[r * 200 + 192] = make_float4(e[0], e[1], e[2], e[3]);
            *(float4*)&sM[r * 200 + 196] = make_float4(e[4], e[5], e[6], e[7]);
            sR4[r * 4] = e[8];
        }
    }
    __syncthreads();

    // ---- back substitution, wave 0, 4-column groups, b128 column reads
    if (tid < 64) {
        float y[4];
#pragma unroll
        for (int q = 0; q < 4; ++q) {
            int r = l + 64 * q;
            y[q] = (r < Kn) ? sR4[r * 4] : 0.f;
        }
        for (int kb = 196; kb >= 0; kb -= 4) {
            float4 cv[4];
#pragma unroll
            for (int q = 0; q < 4; ++q) {
                int r = l + 64 * q;
                cv[q] = (r < Kn) ? *(const float4*)&sM[r * 200 + kb]
                                 : make_float4(0.f, 0.f, 0.f, 0.f);
            }
#pragma unroll
            for (int c = 3; c >= 0; --c) {
                const int kk2 = kb + c;
                const int src = kk2 & 63;
                float xl = 0.f;
#pragma unroll
                for (int q = 0; q < 4; ++q) {
                    int r = l + 64 * q;
                    if (r == kk2) xl = y[q] / ((const float*)&cv[q])[c];
                }
                float xk = __shfl(xl, src);
#pragma unroll
                for (int q = 0; q < 4; ++q) {
                    int r = l + 64 * q;
                    if (r == kk2) y[q] = xk;
                    else if (r < kk2) y[q] -= ((const float*)&cv[q])[c] * xk;
                }
            }
        }
#pragma unroll
        for (int q = 0; q < 4; ++q) {
            int r = l + 64 * q;
            if (r < Kn) out[bid * 200 + r] = y[q];
        }
    }
}

// ---------------------------------------------------------------------------
extern "C" void kernel_launch(void* const* d_in, const int* in_sizes, int n_in,
                              void* d_out, int out_size, void* d_ws, size_t ws_size,
                              hipStream_t stream)
{
    const float* fx   = (const float*)d_in[0];   // feat_x   [8,5000,256]
    const float* fy   = (const float*)d_in[1];   // feat_y
    const float* evx  = (const float*)d_in[2];   // evals_x  [8,200]
    const float* evy  = (const float*)d_in[3];   // evals_y
    const float* etx  = (const float*)d_in[4];   // evecs_trans_x [8,200,5000]
    const float* ety  = (const float*)d_in[5];   // evecs_trans_y
    const float* graw = (const float*)d_in[6];   // gamma_raw scalar
    const float* lraw = (const float*)d_in[7];   // lambda_raw scalar
    float* out = (float*)d_out;
    float* ws  = (float*)d_ws;

    // zero the split-K accumulation region (AB)
    hipMemsetAsync(ws + AB_OFF, 0, (size_t)16 * Kn * Cn * sizeof(float), stream);

    k_gemm_ab<<<dim3(1024), dim3(256), 0, stream>>>(fx, fy, etx, ety, ws + AB_OFF);
    k_gemm_nt<<<dim3(256), dim3(256), 0, stream>>>(ws + AB_OFF, ws + AAT_OFF);
    k_solve<<<dim3(1600), dim3(512), 0, stream>>>(ws + AAT_OFF, evx, evy, graw, lraw, out);
}